// Round 6
// baseline (1419.455 us; speedup 1.0000x reference)
//
#include <hip/hip_runtime.h>
#include <hip/hip_bf16.h>

#define T_TOK 4096
#define HDIM  2048
#define NEXP  64
#define IDIM  768
#define TOPK  4
#define CAPE  512
#define NFLAT (T_TOK*TOPK)

typedef __bf16        bf16x8 __attribute__((ext_vector_type(8)));
typedef float         f32x4  __attribute__((ext_vector_type(4)));
typedef unsigned int  u32x4  __attribute__((ext_vector_type(4)));

// native-cast based conversions (compiler emits v_cvt_pk_bf16_f32-class ops)
__device__ __forceinline__ unsigned short f2bf(float f) {
  __bf16 b = (__bf16)f;
  return __builtin_bit_cast(unsigned short, b);
}
__device__ __forceinline__ unsigned pack2(float lo, float hi) {
  return (unsigned)f2bf(lo) | ((unsigned)f2bf(hi) << 16);
}
// LDS address: row stripe of 128B, 16B chunk xor-swizzled
__device__ __forceinline__ int swz(int row, int chunk) {
  return row*128 + (((chunk ^ (row & 7) ^ ((row >> 3) & 7)) & 7) << 4);
}
// workgroup barrier WITHOUT the vmcnt drain __syncthreads implies:
// LDS ops flushed (visibility), global loads stay in flight across the barrier.
__device__ __forceinline__ void wg_barrier() {
  asm volatile("s_waitcnt lgkmcnt(0)" ::: "memory");
  __builtin_amdgcn_s_barrier();
}

// ---------------- gating: logits, top-4, renorm weights; also hs -> bf16 ----------------
__global__ __launch_bounds__(256) void k_gating(
    const float* __restrict__ hs, const float* __restrict__ gw,
    unsigned short* __restrict__ hs_bf, int* __restrict__ tidx, float* __restrict__ tw)
{
  __shared__ float lg[16][64];
  const int tid = threadIdx.x;
  const int t0  = blockIdx.x * 16;

  {
    const f32x4* src = (const f32x4*)(hs + (size_t)t0 * HDIM);
    for (int i = tid; i < 16 * HDIM / 4; i += 256) {
      f32x4 v = src[i];
      ushort4 o;
      o.x = f2bf(v[0]); o.y = f2bf(v[1]); o.z = f2bf(v[2]); o.w = f2bf(v[3]);
      *(ushort4*)(hs_bf + (size_t)t0 * HDIM + (size_t)i * 4) = o;
    }
  }

  const int lane = tid & 63, wv = tid >> 6;
  {
    const f32x4* gr = (const f32x4*)(gw + (size_t)lane * HDIM);
    const f32x4* x0 = (const f32x4*)(hs + (size_t)(t0 + wv*4 + 0) * HDIM);
    const f32x4* x1 = (const f32x4*)(hs + (size_t)(t0 + wv*4 + 1) * HDIM);
    const f32x4* x2 = (const f32x4*)(hs + (size_t)(t0 + wv*4 + 2) * HDIM);
    const f32x4* x3 = (const f32x4*)(hs + (size_t)(t0 + wv*4 + 3) * HDIM);
    float a0=0.f, a1=0.f, a2=0.f, a3=0.f;
    for (int h = 0; h < HDIM/4; ++h) {
      f32x4 g = gr[h];
      f32x4 v0 = x0[h], v1 = x1[h], v2 = x2[h], v3 = x3[h];
      a0 += g[0]*v0[0] + g[1]*v0[1] + g[2]*v0[2] + g[3]*v0[3];
      a1 += g[0]*v1[0] + g[1]*v1[1] + g[2]*v1[2] + g[3]*v1[3];
      a2 += g[0]*v2[0] + g[1]*v2[1] + g[2]*v2[2] + g[3]*v2[3];
      a3 += g[0]*v3[0] + g[1]*v3[1] + g[2]*v3[2] + g[3]*v3[3];
    }
    lg[wv*4+0][lane] = a0;
    lg[wv*4+1][lane] = a1;
    lg[wv*4+2][lane] = a2;
    lg[wv*4+3][lane] = a3;
  }
  __syncthreads();

  if (tid < 16) {
    const int t = t0 + tid;
    unsigned long long chosen = 0ull;
    float bv[4]; int bi[4];
#pragma unroll
    for (int k = 0; k < 4; ++k) {
      float best = -1e30f; int b = 0;
      for (int e = 0; e < 64; ++e) {
        float v = lg[tid][e];
        if (!((chosen >> e) & 1ull) && v > best) { best = v; b = e; }
      }
      chosen |= 1ull << b; bv[k] = best; bi[k] = b;
    }
    float s = 0.f, w[4];
#pragma unroll
    for (int k = 0; k < 4; ++k) { w[k] = __expf(bv[k] - bv[0]); s += w[k]; }
    float inv = 1.f / s;
#pragma unroll
    for (int k = 0; k < 4; ++k) { tidx[t*4+k] = bi[k]; tw[t*4+k] = w[k] * inv; }
  }
}

// ---------------- per-expert stable rank (ballot scan) ----------------
__global__ __launch_bounds__(64) void k_count_rank(
    const int* __restrict__ tidx, int* __restrict__ rankb, int* __restrict__ counts)
{
  const int e = blockIdx.x;
  const int lane = threadIdx.x;
  int base = 0;
  for (int c = 0; c < NFLAT/64; ++c) {
    int n = c*64 + lane;
    bool m = (tidx[n] == e);
    unsigned long long mask = __ballot(m);
    if (m) rankb[n] = base + __popcll(mask & ((1ull << lane) - 1ull));
    base += __popcll(mask);
  }
  if (lane == 0) counts[e] = base;
}

// ---------------- starts scan + sorted-row maps ----------------
__global__ __launch_bounds__(256) void k_build(
    const int* __restrict__ tidx, const int* __restrict__ rankb,
    const int* __restrict__ counts,
    int* __restrict__ starts, int* __restrict__ row_info, int* __restrict__ sortpos)
{
  __shared__ int s_starts[NEXP];
  if (threadIdx.x == 0) {
    int s = 0;
    for (int e = 0; e < NEXP; ++e) { s_starts[e] = s; starts[e] = s; s += counts[e]; }
  }
  __syncthreads();
  for (int n = threadIdx.x; n < NFLAT; n += 256) {
    int e = tidx[n], r = rankb[n];
    int sr = s_starts[e] + r;
    row_info[sr] = n;
    sortpos[n] = (r < CAPE) ? sr : -1;
  }
}

// ---------------- GEMM1 (gather A) + fused SwiGLU -> a_buf (bf16) ----------------
// grid (nt, e); internal m-loop (256 rows/iter); dbuf LDS; raw barrier (no vmcnt drain);
// per K-step: MFMA(cur) -> write(kt+1 from regs loaded a full step ago) -> barrier -> issue(kt+2).
__global__ __launch_bounds__(512, 2) void k_gemm1(
    const unsigned short* __restrict__ hs_bf, const float* __restrict__ w13,
    const int* __restrict__ counts, const int* __restrict__ starts,
    const int* __restrict__ row_info, unsigned short* __restrict__ a_buf)
{
  const int nt = blockIdx.x;   // 0..5   (128 i-cols, both halves)
  const int e  = blockIdx.y;   // 0..63
  const int count = min(counts[e], CAPE);
  if (count <= 0) return;
  const int nmt = (count + 255) >> 8;
  const int tid = threadIdx.x;
  const int estart = starts[e];
  const int NK = HDIM/64;      // 32 (even)

  // per buffer: A [256][128B] @0 (32KB), Bg [128][128B] @32768, Bu @49152 -> 64KB; x2
  __shared__ __align__(16) char lds[2*65536];

  const int mrow = tid >> 3, cchunk = tid & 7;
  const float* w13e = w13 + (size_t)e * HDIM * (2*IDIM);
  const int half = tid >> 8;        // 0=gate half, 1=up half
  const int t8   = tid & 255;
  const int kg   = t8 >> 5;         // k-group of 8
  const int n4   = (t8 & 31) * 4;
  const int lane = tid & 63, wv = tid >> 6;
  const int wr = wv >> 1, wc = wv & 1;
  const float* bbase = w13e + (size_t)(kg*8) * (2*IDIM) + half*IDIM + nt*128 + n4;

  for (int mi = 0; mi < nmt; ++mi) {
    const int R0 = mi << 8;
    const int base_sorted = estart + R0;
    int tokp[4];
#pragma unroll
    for (int p = 0; p < 4; ++p) {
      int sr = base_sorted + mrow + p*64;
      if (sr > NFLAT-1) sr = NFLAT-1;
      tokp[p] = row_info[sr] >> 2;
    }
    f32x4 accg[4][4], accu[4][4];
#pragma unroll
    for (int i = 0; i < 4; ++i)
#pragma unroll
      for (int j = 0; j < 4; ++j) { accg[i][j] = f32x4{0.f,0.f,0.f,0.f}; accu[i][j] = f32x4{0.f,0.f,0.f,0.f}; }

    u32x4 rA[4]; f32x4 rB[8];
    // prologue: load+write k-tile 0
#pragma unroll
    for (int p = 0; p < 4; ++p)
      rA[p] = *(const u32x4*)(hs_bf + (size_t)tokp[p]*HDIM + cchunk*8);
#pragma unroll
    for (int j = 0; j < 8; ++j) rB[j] = *(const f32x4*)(bbase + (size_t)j * (2*IDIM));
    {
      char* A0 = lds;
      char* B0 = lds + 32768 + half*16384;
#pragma unroll
      for (int p = 0; p < 4; ++p)
        *(u32x4*)(A0 + swz(mrow + p*64, cchunk)) = rA[p];
#pragma unroll
      for (int i = 0; i < 4; ++i) {
        u32x4 q;
        q[0] = pack2(rB[0][i], rB[1][i]);
        q[1] = pack2(rB[2][i], rB[3][i]);
        q[2] = pack2(rB[4][i], rB[5][i]);
        q[3] = pack2(rB[6][i], rB[7][i]);
        *(u32x4*)(B0 + swz(n4 + i, kg)) = q;
      }
    }
    wg_barrier();
    // issue loads for k-tile 1 (stay in flight through K-step 0)
#pragma unroll
    for (int p = 0; p < 4; ++p)
      rA[p] = *(const u32x4*)(hs_bf + (size_t)tokp[p]*HDIM + 64 + cchunk*8);
#pragma unroll
    for (int j = 0; j < 8; ++j) rB[j] = *(const f32x4*)(bbase + 64*(2*IDIM) + (size_t)j * (2*IDIM));

    int cur = 0;
    for (int kt = 0; kt < NK; ++kt) {
      char* Ac  = lds + cur*65536;
      char* Bgc = Ac + 32768;
      char* Buc = Bgc + 16384;
      __builtin_amdgcn_s_setprio(1);
#pragma unroll
      for (int kfi = 0; kfi < 2; ++kfi) {
        const int ch = (kfi<<2) | (lane>>4);
        bf16x8 af[4], bg[4], bu[4];
#pragma unroll
        for (int m2 = 0; m2 < 4; ++m2)
          af[m2] = *(const bf16x8*)(Ac + swz(wr*64 + m2*16 + (lane & 15), ch));
#pragma unroll
        for (int ni = 0; ni < 4; ++ni) {
          int n = wc*64 + ni*16 + (lane & 15);
          bg[ni] = *(const bf16x8*)(Bgc + swz(n, ch));
          bu[ni] = *(const bf16x8*)(Buc + swz(n, ch));
        }
#pragma unroll
        for (int m2 = 0; m2 < 4; ++m2)
#pragma unroll
          for (int ni = 0; ni < 4; ++ni) {
            accg[m2][ni] = __builtin_amdgcn_mfma_f32_16x16x32_bf16(af[m2], bg[ni], accg[m2][ni], 0, 0, 0);
            accu[m2][ni] = __builtin_amdgcn_mfma_f32_16x16x32_bf16(af[m2], bu[ni], accu[m2][ni], 0, 0, 0);
          }
      }
      __builtin_amdgcn_s_setprio(0);
      if (kt+1 < NK) {
        // write k-tile kt+1 (loads issued one full K-step ago -> latency hidden)
        char* An = lds + (cur^1)*65536;
        char* Bn = An + 32768 + half*16384;
#pragma unroll
        for (int p = 0; p < 4; ++p)
          *(u32x4*)(An + swz(mrow + p*64, cchunk)) = rA[p];
#pragma unroll
        for (int i = 0; i < 4; ++i) {
          u32x4 q;
          q[0] = pack2(rB[0][i], rB[1][i]);
          q[1] = pack2(rB[2][i], rB[3][i]);
          q[2] = pack2(rB[4][i], rB[5][i]);
          q[3] = pack2(rB[6][i], rB[7][i]);
          *(u32x4*)(Bn + swz(n4 + i, kg)) = q;
        }
      }
      wg_barrier();
      if (kt+2 < NK) {
        // issue loads for k-tile kt+2 (fly across the next K-step)
#pragma unroll
        for (int p = 0; p < 4; ++p)
          rA[p] = *(const u32x4*)(hs_bf + (size_t)tokp[p]*HDIM + (kt+2)*64 + cchunk*8);
        const float* bp = bbase + (size_t)(kt+2)*64 * (2*IDIM);
#pragma unroll
        for (int j = 0; j < 8; ++j) rB[j] = *(const f32x4*)(bp + (size_t)j * (2*IDIM));
      }
      cur ^= 1;
    }

    // epilogue: silu(g)*u -> a_buf (bf16)
#pragma unroll
    for (int m2 = 0; m2 < 4; ++m2) {
#pragma unroll
      for (int j = 0; j < 4; ++j) {
        int rl = wr*64 + m2*16 + (lane >> 4)*4 + j;
        if (R0 + rl < count) {
          size_t rowoff = (size_t)(base_sorted + rl) * IDIM;
#pragma unroll
          for (int ni = 0; ni < 4; ++ni) {
            int col = nt*128 + wc*64 + ni*16 + (lane & 15);
            float g = accg[m2][ni][j], u = accu[m2][ni][j];
            float a = (g / (1.f + __expf(-g))) * u;
            a_buf[rowoff + col] = f2bf(a);
          }
        }
      }
    }
  }
}

// ---------------- GEMM2 -> y_buf (bf16, sorted rows, unweighted) ----------------
__global__ __launch_bounds__(512, 2) void k_gemm2(
    const unsigned short* __restrict__ a_buf, const float* __restrict__ w2,
    const int* __restrict__ counts, const int* __restrict__ starts,
    unsigned short* __restrict__ y_buf)
{
  const int nt = blockIdx.x;   // 0..7  (256 cols each)
  const int e  = blockIdx.y;   // 0..63
  const int count = min(counts[e], CAPE);
  if (count <= 0) return;
  const int nmt = (count + 255) >> 8;
  const int tid = threadIdx.x;
  const int estart = starts[e];
  const int NK = IDIM/64;      // 12 (even)

  // per buffer: A [256][128B] @0 (32KB), B [256][128B] @32768 (32KB); x2
  __shared__ __align__(16) char lds[2*65536];

  const int mrow = tid >> 3, cchunk = tid & 7;
  const float* w2e = w2 + (size_t)e * IDIM * HDIM;
  const int pass = tid >> 8;
  const int t8   = tid & 255;
  const int kg   = t8 >> 5, n4 = (t8 & 31) * 4;
  const int lane = tid & 63, wv = tid >> 6, wr = wv >> 1, wc = wv & 1;
  const float* bbase = w2e + (size_t)(kg*8) * HDIM + nt*256 + pass*128 + n4;

  for (int mi = 0; mi < nmt; ++mi) {
    const int R0 = mi << 8;
    const int base_sorted = estart + R0;
    int srp[4];
#pragma unroll
    for (int p = 0; p < 4; ++p) {
      int sr = base_sorted + mrow + p*64;
      srp[p] = (sr > NFLAT-1) ? (NFLAT-1) : sr;
    }
    f32x4 acc[4][8];
#pragma unroll
    for (int i = 0; i < 4; ++i)
#pragma unroll
      for (int j = 0; j < 8; ++j) acc[i][j] = f32x4{0.f,0.f,0.f,0.f};

    u32x4 rA[4]; f32x4 rB[8];
    // prologue: load+write k-tile 0
#pragma unroll
    for (int p = 0; p < 4; ++p)
      rA[p] = *(const u32x4*)(a_buf + (size_t)srp[p]*IDIM + cchunk*8);
#pragma unroll
    for (int j = 0; j < 8; ++j) rB[j] = *(const f32x4*)(bbase + (size_t)j * HDIM);
    {
      char* A0 = lds;
      char* B0 = lds + 32768;
#pragma unroll
      for (int p = 0; p < 4; ++p)
        *(u32x4*)(A0 + swz(mrow + p*64, cchunk)) = rA[p];
#pragma unroll
      for (int i = 0; i < 4; ++i) {
        int n = pass*128 + n4 + i;
        u32x4 q;
        q[0] = pack2(rB[0][i], rB[1][i]);
        q[1] = pack2(rB[2][i], rB[3][i]);
        q[2] = pack2(rB[4][i], rB[5][i]);
        q[3] = pack2(rB[6][i], rB[7][i]);
        *(u32x4*)(B0 + swz(n, kg)) = q;
      }
    }
    wg_barrier();
    // issue loads for k-tile 1
#pragma unroll
    for (int p = 0; p < 4; ++p)
      rA[p] = *(const u32x4*)(a_buf + (size_t)srp[p]*IDIM + 64 + cchunk*8);
#pragma unroll
    for (int j = 0; j < 8; ++j) rB[j] = *(const f32x4*)(bbase + 64*HDIM + (size_t)j * HDIM);

    int cur = 0;
    for (int kt = 0; kt < NK; ++kt) {
      char* Ac = lds + cur*65536;
      char* Bc = Ac + 32768;
      __builtin_amdgcn_s_setprio(1);
#pragma unroll
      for (int kfi = 0; kfi < 2; ++kfi) {
        const int ch = (kfi<<2) | (lane>>4);
        bf16x8 af[4], bb[8];
#pragma unroll
        for (int m2 = 0; m2 < 4; ++m2)
          af[m2] = *(const bf16x8*)(Ac + swz(wr*64 + m2*16 + (lane & 15), ch));
#pragma unroll
        for (int ni = 0; ni < 8; ++ni) {
          int n = wc*128 + ni*16 + (lane & 15);
          bb[ni] = *(const bf16x8*)(Bc + swz(n, ch));
        }
#pragma unroll
        for (int m2 = 0; m2 < 4; ++m2)
#pragma unroll
          for (int ni = 0; ni < 8; ++ni)
            acc[m2][ni] = __builtin_amdgcn_mfma_f32_16x16x32_bf16(af[m2], bb[ni], acc[m2][ni], 0, 0, 0);
      }
      __builtin_amdgcn_s_setprio(0);
      if (kt+1 < NK) {
        char* An = lds + (cur^1)*65536;
        char* Bn = An + 32768;
#pragma unroll
        for (int p = 0; p < 4; ++p)
          *(u32x4*)(An + swz(mrow + p*64, cchunk)) = rA[p];
#pragma unroll
        for (int i = 0; i < 4; ++i) {
          int n = pass*128 + n4 + i;
          u32x4 q;
          q[0] = pack2(rB[0][i], rB[1][i]);
          q[1] = pack2(rB[2][i], rB[3][i]);
          q[2] = pack2(rB[4][i], rB[5][i]);
          q[3] = pack2(rB[6][i], rB[7][i]);
          *(u32x4*)(Bn + swz(n, kg)) = q;
        }
      }
      wg_barrier();
      if (kt+2 < NK) {
#pragma unroll
        for (int p = 0; p < 4; ++p)
          rA[p] = *(const u32x4*)(a_buf + (size_t)srp[p]*IDIM + (kt+2)*64 + cchunk*8);
        const float* bp = bbase + (size_t)(kt+2)*64 * HDIM;
#pragma unroll
        for (int j = 0; j < 8; ++j) rB[j] = *(const f32x4*)(bp + (size_t)j * HDIM);
      }
      cur ^= 1;
    }

    // epilogue: bf16 stores of unweighted y rows
#pragma unroll
    for (int m2 = 0; m2 < 4; ++m2) {
#pragma unroll
      for (int j = 0; j < 4; ++j) {
        int rl = wr*64 + m2*16 + (lane >> 4)*4 + j;
        if (R0 + rl < count) {
          int sr = base_sorted + rl;
          unsigned short* yrow = y_buf + (size_t)sr * HDIM;
#pragma unroll
          for (int ni = 0; ni < 8; ++ni) {
            int col = nt*256 + wc*128 + ni*16 + (lane & 15);
            yrow[col] = f2bf(acc[m2][ni][j]);
          }
        }
      }
    }
  }
}

// ---------------- finalize: out[t] = sum_k tw[t,k] * y_buf[sortpos[t,k]] ----------------
__global__ __launch_bounds__(256) void k_finalize(
    const unsigned short* __restrict__ y_buf, const int* __restrict__ sortpos,
    const float* __restrict__ tw, float* __restrict__ out)
{
  const int t = blockIdx.x;
  const int tid = threadIdx.x;
  float acc[8];
#pragma unroll
  for (int i = 0; i < 8; ++i) acc[i] = 0.f;
#pragma unroll
  for (int k = 0; k < 4; ++k) {
    int sp = sortpos[t*4+k];
    float w = tw[t*4+k];
    if (sp >= 0) {
      u32x4 v = *(const u32x4*)(y_buf + (size_t)sp * HDIM + tid*8);
#pragma unroll
      for (int q = 0; q < 4; ++q) {
        float lo = __builtin_bit_cast(float, v[q] << 16);
        float hi = __builtin_bit_cast(float, v[q] & 0xffff0000u);
        acc[2*q]   += w * lo;
        acc[2*q+1] += w * hi;
      }
    }
  }
  f32x4 o0 = {acc[0], acc[1], acc[2], acc[3]};
  f32x4 o1 = {acc[4], acc[5], acc[6], acc[7]};
  f32x4* o = (f32x4*)(out + (size_t)t * HDIM + tid*8);
  o[0] = o0;
  o[1] = o1;
}

extern "C" void kernel_launch(void* const* d_in, const int* in_sizes, int n_in,
                              void* d_out, int out_size, void* d_ws, size_t ws_size,
                              hipStream_t stream) {
  const float* hs  = (const float*)d_in[0];
  const float* gw  = (const float*)d_in[1];
  const float* w13 = (const float*)d_in[2];
  const float* w2  = (const float*)d_in[3];
  float* out = (float*)d_out;

  char* ws = (char*)d_ws;
  size_t off = 0;
  auto alloc = [&](size_t bytes) {
    off = (off + 255) & ~(size_t)255;
    char* p = ws + off;
    off += bytes;
    return p;
  };
  unsigned short* hs_bf = (unsigned short*)alloc((size_t)T_TOK * HDIM * 2);
  int*   tidx   = (int*)  alloc((size_t)NFLAT * 4);
  float* tw     = (float*)alloc((size_t)NFLAT * 4);
  int*   rankb  = (int*)  alloc((size_t)NFLAT * 4);
  int*   counts = (int*)  alloc((size_t)NEXP * 4);
  int*   starts = (int*)  alloc((size_t)NEXP * 4);
  int*   rinfo  = (int*)  alloc((size_t)NFLAT * 4);
  int*   sortp  = (int*)  alloc((size_t)NFLAT * 4);
  unsigned short* a_buf = (unsigned short*)alloc((size_t)NFLAT * IDIM * 2);
  unsigned short* y_buf = (unsigned short*)alloc((size_t)NFLAT * HDIM * 2);
  (void)ws_size; (void)in_sizes; (void)n_in; (void)out_size;

  k_gating<<<T_TOK/16, 256, 0, stream>>>(hs, gw, hs_bf, tidx, tw);
  k_count_rank<<<NEXP, 64, 0, stream>>>(tidx, rankb, counts);
  k_build<<<1, 256, 0, stream>>>(tidx, rankb, counts, starts, rinfo, sortp);
  k_gemm1<<<dim3(6, NEXP), 512, 0, stream>>>(hs_bf, w13, counts, starts, rinfo, a_buf);
  k_gemm2<<<dim3(8, NEXP), 512, 0, stream>>>(a_buf, w2, counts, starts, y_buf);
  k_finalize<<<T_TOK, 256, 0, stream>>>(y_buf, sortp, tw, out);
}

// Round 7
// 943.713 us; speedup vs baseline: 1.5041x; 1.5041x over previous
//
#include <hip/hip_runtime.h>
#include <hip/hip_bf16.h>

#define T_TOK 4096
#define HDIM  2048
#define NEXP  64
#define IDIM  768
#define TOPK  4
#define CAPE  512
#define NFLAT (T_TOK*TOPK)

typedef __bf16        bf16x8 __attribute__((ext_vector_type(8)));
typedef float         f32x4  __attribute__((ext_vector_type(4)));
typedef unsigned int  u32x4  __attribute__((ext_vector_type(4)));

__device__ __forceinline__ unsigned short f2bf(float f) {
  __bf16 b = (__bf16)f;
  return __builtin_bit_cast(unsigned short, b);
}
__device__ __forceinline__ unsigned pack2(float lo, float hi) {
  return (unsigned)f2bf(lo) | ((unsigned)f2bf(hi) << 16);
}
// LDS addr: row stripe of 128B, 16B chunk xor-swizzled (conflict-free frag reads)
__device__ __forceinline__ int swz(int row, int chunk) {
  return row*128 + (((chunk ^ (row & 7) ^ ((row >> 3) & 7)) & 7) << 4);
}
// async global->LDS, 16B per lane; LDS dest linear (wave base + lane*16),
// swizzle achieved by pre-swizzling the per-lane GLOBAL source address.
__device__ __forceinline__ void gload_lds16(const void* g, void* l) {
  __builtin_amdgcn_global_load_lds(
      (const __attribute__((address_space(1))) unsigned int*)g,
      (__attribute__((address_space(3))) unsigned int*)l, 16, 0, 0);
}

// ---------------- gating: logits, top-4, renorm weights; also hs -> bf16 ----------------
__global__ __launch_bounds__(256) void k_gating(
    const float* __restrict__ hs, const float* __restrict__ gw,
    unsigned short* __restrict__ hs_bf, int* __restrict__ tidx, float* __restrict__ tw)
{
  __shared__ float lg[16][64];
  const int tid = threadIdx.x;
  const int t0  = blockIdx.x * 16;

  {
    const f32x4* src = (const f32x4*)(hs + (size_t)t0 * HDIM);
    for (int i = tid; i < 16 * HDIM / 4; i += 256) {
      f32x4 v = src[i];
      ushort4 o;
      o.x = f2bf(v[0]); o.y = f2bf(v[1]); o.z = f2bf(v[2]); o.w = f2bf(v[3]);
      *(ushort4*)(hs_bf + (size_t)t0 * HDIM + (size_t)i * 4) = o;
    }
  }

  const int lane = tid & 63, wv = tid >> 6;
  {
    const f32x4* gr = (const f32x4*)(gw + (size_t)lane * HDIM);
    const f32x4* x0 = (const f32x4*)(hs + (size_t)(t0 + wv*4 + 0) * HDIM);
    const f32x4* x1 = (const f32x4*)(hs + (size_t)(t0 + wv*4 + 1) * HDIM);
    const f32x4* x2 = (const f32x4*)(hs + (size_t)(t0 + wv*4 + 2) * HDIM);
    const f32x4* x3 = (const f32x4*)(hs + (size_t)(t0 + wv*4 + 3) * HDIM);
    float a0=0.f, a1=0.f, a2=0.f, a3=0.f;
    for (int h = 0; h < HDIM/4; ++h) {
      f32x4 g = gr[h];
      f32x4 v0 = x0[h], v1 = x1[h], v2 = x2[h], v3 = x3[h];
      a0 += g[0]*v0[0] + g[1]*v0[1] + g[2]*v0[2] + g[3]*v0[3];
      a1 += g[0]*v1[0] + g[1]*v1[1] + g[2]*v1[2] + g[3]*v1[3];
      a2 += g[0]*v2[0] + g[1]*v2[1] + g[2]*v2[2] + g[3]*v2[3];
      a3 += g[0]*v3[0] + g[1]*v3[1] + g[2]*v3[2] + g[3]*v3[3];
    }
    lg[wv*4+0][lane] = a0;
    lg[wv*4+1][lane] = a1;
    lg[wv*4+2][lane] = a2;
    lg[wv*4+3][lane] = a3;
  }
  __syncthreads();

  if (tid < 16) {
    const int t = t0 + tid;
    unsigned long long chosen = 0ull;
    float bv[4]; int bi[4];
#pragma unroll
    for (int k = 0; k < 4; ++k) {
      float best = -1e30f; int b = 0;
      for (int e = 0; e < 64; ++e) {
        float v = lg[tid][e];
        if (!((chosen >> e) & 1ull) && v > best) { best = v; b = e; }
      }
      chosen |= 1ull << b; bv[k] = best; bi[k] = b;
    }
    float s = 0.f, w[4];
#pragma unroll
    for (int k = 0; k < 4; ++k) { w[k] = __expf(bv[k] - bv[0]); s += w[k]; }
    float inv = 1.f / s;
#pragma unroll
    for (int k = 0; k < 4; ++k) { tidx[t*4+k] = bi[k]; tw[t*4+k] = w[k] * inv; }
  }
}

// ---------------- per-expert stable rank (ballot scan) ----------------
__global__ __launch_bounds__(64) void k_count_rank(
    const int* __restrict__ tidx, int* __restrict__ rankb, int* __restrict__ counts)
{
  const int e = blockIdx.x;
  const int lane = threadIdx.x;
  int base = 0;
  for (int c = 0; c < NFLAT/64; ++c) {
    int n = c*64 + lane;
    bool m = (tidx[n] == e);
    unsigned long long mask = __ballot(m);
    if (m) rankb[n] = base + __popcll(mask & ((1ull << lane) - 1ull));
    base += __popcll(mask);
  }
  if (lane == 0) counts[e] = base;
}

// ---------------- starts scan + sorted-row maps ----------------
__global__ __launch_bounds__(256) void k_build(
    const int* __restrict__ tidx, const int* __restrict__ rankb,
    const int* __restrict__ counts,
    int* __restrict__ starts, int* __restrict__ row_info, int* __restrict__ sortpos)
{
  __shared__ int s_starts[NEXP];
  if (threadIdx.x == 0) {
    int s = 0;
    for (int e = 0; e < NEXP; ++e) { s_starts[e] = s; starts[e] = s; s += counts[e]; }
  }
  __syncthreads();
  for (int n = threadIdx.x; n < NFLAT; n += 256) {
    int e = tidx[n], r = rankb[n];
    int sr = s_starts[e] + r;
    row_info[sr] = n;
    sortpos[n] = (r < CAPE) ? sr : -1;
  }
}

// ---------------- GEMM1 (gather A) + fused SwiGLU -> a_buf (bf16) ----------------
// m97 structure: 256 thr, tile 128 rows x 64 icols x {g,u}, BK=64, 32KB LDS single-buffer,
// 2 barriers/K-step, A via global_load_lds (pre-swizzled source), ~3 blocks/CU.
__global__ __launch_bounds__(256, 3) void k_gemm1(
    const unsigned short* __restrict__ hs_bf, const float* __restrict__ w13,
    const int* __restrict__ counts, const int* __restrict__ starts,
    const int* __restrict__ row_info, unsigned short* __restrict__ a_buf)
{
  const int nt = blockIdx.x;   // 0..11 (64 i-cols)
  const int e  = blockIdx.y;   // 0..63
  const int count = min(counts[e], CAPE);
  if (count <= 0) return;
  const int nmt = (count + 127) >> 7;
  const int tid = threadIdx.x;
  const int estart = starts[e];

  // A[128][128B] @0 (16KB), Bg[64][128B] @16384 (8KB), Bu @24576 (8KB)
  __shared__ __align__(16) char lds[32768];

  const int lane = tid & 63, wv = tid >> 6;
  const int wr = wv >> 1, wc = wv & 1;   // wave tile: rows wr*64, cols wc*32 (both halves)

  // B staging: threads 0-127 -> gate half, 128-255 -> up half
  const int bhalf = tid >> 7;
  const int t7 = tid & 127;
  const int bkg = t7 >> 4;             // 0..7 (8 consecutive k each)
  const int bc4 = (t7 & 15) * 4;       // 0..60
  const float* w13e = w13 + (size_t)e * HDIM * (2*IDIM) + (size_t)bhalf*IDIM + (size_t)nt*64 + bc4;

  // A gload: per thread 4 rounds; round r covers rows wv*32 + r*8 .. +8
  int srcch[4];
#pragma unroll
  for (int r = 0; r < 4; ++r)
    srcch[r] = (lane & 7) ^ (lane >> 3) ^ ((wv*4 + r) & 7);

  for (int mit = 0; mit < nmt; ++mit) {
    const int R0 = mit << 7;
    const int base_sorted = estart + R0;
    int tokp[4];
#pragma unroll
    for (int r = 0; r < 4; ++r) {
      int sr = base_sorted + wv*32 + r*8 + (lane >> 3);
      if (sr > NFLAT-1) sr = NFLAT-1;
      tokp[r] = row_info[sr] >> 2;
    }

    f32x4 accg[4][2], accu[4][2];
#pragma unroll
    for (int i = 0; i < 4; ++i)
#pragma unroll
      for (int j = 0; j < 2; ++j) { accg[i][j] = f32x4{0.f,0.f,0.f,0.f}; accu[i][j] = f32x4{0.f,0.f,0.f,0.f}; }

    for (int kt = 0; kt < HDIM/64; ++kt) {
      // stage A: async direct-to-LDS, source pre-swizzled
#pragma unroll
      for (int r = 0; r < 4; ++r)
        gload_lds16(hs_bf + (size_t)tokp[r]*HDIM + kt*64 + srcch[r]*8,
                    lds + wv*4096 + r*1024 + lane*16);
      // stage B: fp32 -> bf16 k-pair packed
      {
        const float* bp = w13e + (size_t)(kt*64 + bkg*8) * (2*IDIM);
        f32x4 f[8];
#pragma unroll
        for (int j = 0; j < 8; ++j) f[j] = *(const f32x4*)(bp + (size_t)j * (2*IDIM));
        char* Bh = lds + 16384 + bhalf*8192;
#pragma unroll
        for (int i = 0; i < 4; ++i) {
          u32x4 q;
          q[0] = pack2(f[0][i], f[1][i]);
          q[1] = pack2(f[2][i], f[3][i]);
          q[2] = pack2(f[4][i], f[5][i]);
          q[3] = pack2(f[6][i], f[7][i]);
          *(u32x4*)(Bh + swz(bc4 + i, bkg)) = q;
        }
      }
      __syncthreads();   // drains vmcnt (A arrived) + lgkm (B visible)
      char* Bgl = lds + 16384;
      char* Bul = lds + 24576;
#pragma unroll
      for (int kfi = 0; kfi < 2; ++kfi) {
        const int ch = (kfi<<2) | (lane>>4);
        bf16x8 af[4], bg[2], bu[2];
#pragma unroll
        for (int m2 = 0; m2 < 4; ++m2)
          af[m2] = *(const bf16x8*)(lds + swz(wr*64 + m2*16 + (lane & 15), ch));
#pragma unroll
        for (int ni = 0; ni < 2; ++ni) {
          int col = wc*32 + ni*16 + (lane & 15);
          bg[ni] = *(const bf16x8*)(Bgl + swz(col, ch));
          bu[ni] = *(const bf16x8*)(Bul + swz(col, ch));
        }
#pragma unroll
        for (int m2 = 0; m2 < 4; ++m2)
#pragma unroll
          for (int ni = 0; ni < 2; ++ni) {
            accg[m2][ni] = __builtin_amdgcn_mfma_f32_16x16x32_bf16(af[m2], bg[ni], accg[m2][ni], 0, 0, 0);
            accu[m2][ni] = __builtin_amdgcn_mfma_f32_16x16x32_bf16(af[m2], bu[ni], accu[m2][ni], 0, 0, 0);
          }
      }
      __syncthreads();   // protect LDS before next K-step's staging
    }

    // epilogue: silu(g)*u -> a_buf (bf16)
#pragma unroll
    for (int m2 = 0; m2 < 4; ++m2) {
#pragma unroll
      for (int j = 0; j < 4; ++j) {
        int rl = wr*64 + m2*16 + (lane >> 4)*4 + j;
        if (R0 + rl < count) {
          size_t rowoff = (size_t)(base_sorted + rl) * IDIM;
#pragma unroll
          for (int ni = 0; ni < 2; ++ni) {
            int col = nt*64 + wc*32 + ni*16 + (lane & 15);
            float g = accg[m2][ni][j], u = accu[m2][ni][j];
            float a = (g / (1.f + __expf(-g))) * u;
            a_buf[rowoff + col] = f2bf(a);
          }
        }
      }
    }
  }
}

// ---------------- GEMM2 -> y_buf (bf16, sorted rows, unweighted) ----------------
// m97 structure: 256 thr, tile 128 rows x 128 cols, BK=64, 32KB LDS single-buffer.
__global__ __launch_bounds__(256, 3) void k_gemm2(
    const unsigned short* __restrict__ a_buf, const float* __restrict__ w2,
    const int* __restrict__ counts, const int* __restrict__ starts,
    unsigned short* __restrict__ y_buf)
{
  const int nt = blockIdx.x;   // 0..15 (128 cols)
  const int e  = blockIdx.y;   // 0..63
  const int count = min(counts[e], CAPE);
  if (count <= 0) return;
  const int nmt = (count + 127) >> 7;
  const int tid = threadIdx.x;
  const int estart = starts[e];

  // A[128][128B] @0 (16KB), B[128][128B] @16384 (16KB)
  __shared__ __align__(16) char lds[32768];

  const int lane = tid & 63, wv = tid >> 6;
  const int wr = wv >> 1, wc = wv & 1;   // wave tile 64x64

  const int bkg = tid >> 5;             // 0..7
  const int bc4 = (tid & 31) * 4;       // 0..124
  const float* w2e = w2 + (size_t)e * IDIM * HDIM + (size_t)nt*128 + bc4;

  int srcch[4];
#pragma unroll
  for (int r = 0; r < 4; ++r)
    srcch[r] = (lane & 7) ^ (lane >> 3) ^ ((wv*4 + r) & 7);

  for (int mit = 0; mit < nmt; ++mit) {
    const int R0 = mit << 7;
    const int base_sorted = estart + R0;
    int srp[4];
#pragma unroll
    for (int r = 0; r < 4; ++r) {
      int sr = base_sorted + wv*32 + r*8 + (lane >> 3);
      srp[r] = (sr > NFLAT-1) ? (NFLAT-1) : sr;
    }

    f32x4 acc[4][4];
#pragma unroll
    for (int i = 0; i < 4; ++i)
#pragma unroll
      for (int j = 0; j < 4; ++j) acc[i][j] = f32x4{0.f,0.f,0.f,0.f};

    for (int kt = 0; kt < IDIM/64; ++kt) {
      // stage A: async direct-to-LDS (a_buf rows are sorted-contiguous bf16)
#pragma unroll
      for (int r = 0; r < 4; ++r)
        gload_lds16(a_buf + (size_t)srp[r]*IDIM + kt*64 + srcch[r]*8,
                    lds + wv*4096 + r*1024 + lane*16);
      // stage B: fp32 -> bf16 k-pair packed
      {
        const float* bp = w2e + (size_t)(kt*64 + bkg*8) * HDIM;
        f32x4 f[8];
#pragma unroll
        for (int j = 0; j < 8; ++j) f[j] = *(const f32x4*)(bp + (size_t)j * HDIM);
        char* Bl = lds + 16384;
#pragma unroll
        for (int i = 0; i < 4; ++i) {
          u32x4 q;
          q[0] = pack2(f[0][i], f[1][i]);
          q[1] = pack2(f[2][i], f[3][i]);
          q[2] = pack2(f[4][i], f[5][i]);
          q[3] = pack2(f[6][i], f[7][i]);
          *(u32x4*)(Bl + swz(bc4 + i, bkg)) = q;
        }
      }
      __syncthreads();
      char* Bl = lds + 16384;
#pragma unroll
      for (int kfi = 0; kfi < 2; ++kfi) {
        const int ch = (kfi<<2) | (lane>>4);
        bf16x8 af[4], bb[4];
#pragma unroll
        for (int m2 = 0; m2 < 4; ++m2)
          af[m2] = *(const bf16x8*)(lds + swz(wr*64 + m2*16 + (lane & 15), ch));
#pragma unroll
        for (int ni = 0; ni < 4; ++ni)
          bb[ni] = *(const bf16x8*)(Bl + swz(wc*64 + ni*16 + (lane & 15), ch));
#pragma unroll
        for (int m2 = 0; m2 < 4; ++m2)
#pragma unroll
          for (int ni = 0; ni < 4; ++ni)
            acc[m2][ni] = __builtin_amdgcn_mfma_f32_16x16x32_bf16(af[m2], bb[ni], acc[m2][ni], 0, 0, 0);
      }
      __syncthreads();
    }

    // epilogue: bf16 stores of unweighted y rows
#pragma unroll
    for (int m2 = 0; m2 < 4; ++m2) {
#pragma unroll
      for (int j = 0; j < 4; ++j) {
        int rl = wr*64 + m2*16 + (lane >> 4)*4 + j;
        if (R0 + rl < count) {
          int sr = base_sorted + rl;
          unsigned short* yrow = y_buf + (size_t)sr * HDIM;
#pragma unroll
          for (int ni = 0; ni < 4; ++ni) {
            int col = nt*128 + wc*64 + ni*16 + (lane & 15);
            yrow[col] = f2bf(acc[m2][ni][j]);
          }
        }
      }
    }
  }
}

// ---------------- finalize: out[t] = sum_k tw[t,k] * y_buf[sortpos[t,k]] ----------------
__global__ __launch_bounds__(256) void k_finalize(
    const unsigned short* __restrict__ y_buf, const int* __restrict__ sortpos,
    const float* __restrict__ tw, float* __restrict__ out)
{
  const int t = blockIdx.x;
  const int tid = threadIdx.x;
  float acc[8];
#pragma unroll
  for (int i = 0; i < 8; ++i) acc[i] = 0.f;
#pragma unroll
  for (int k = 0; k < 4; ++k) {
    int sp = sortpos[t*4+k];
    float w = tw[t*4+k];
    if (sp >= 0) {
      u32x4 v = *(const u32x4*)(y_buf + (size_t)sp * HDIM + tid*8);
#pragma unroll
      for (int q = 0; q < 4; ++q) {
        float lo = __builtin_bit_cast(float, v[q] << 16);
        float hi = __builtin_bit_cast(float, v[q] & 0xffff0000u);
        acc[2*q]   += w * lo;
        acc[2*q+1] += w * hi;
      }
    }
  }
  f32x4 o0 = {acc[0], acc[1], acc[2], acc[3]};
  f32x4 o1 = {acc[4], acc[5], acc[6], acc[7]};
  f32x4* o = (f32x4*)(out + (size_t)t * HDIM + tid*8);
  o[0] = o0;
  o[1] = o1;
}

extern "C" void kernel_launch(void* const* d_in, const int* in_sizes, int n_in,
                              void* d_out, int out_size, void* d_ws, size_t ws_size,
                              hipStream_t stream) {
  const float* hs  = (const float*)d_in[0];
  const float* gw  = (const float*)d_in[1];
  const float* w13 = (const float*)d_in[2];
  const float* w2  = (const float*)d_in[3];
  float* out = (float*)d_out;

  char* ws = (char*)d_ws;
  size_t off = 0;
  auto alloc = [&](size_t bytes) {
    off = (off + 255) & ~(size_t)255;
    char* p = ws + off;
    off += bytes;
    return p;
  };
  unsigned short* hs_bf = (unsigned short*)alloc((size_t)T_TOK * HDIM * 2);
  int*   tidx   = (int*)  alloc((size_t)NFLAT * 4);
  float* tw     = (float*)alloc((size_t)NFLAT * 4);
  int*   rankb  = (int*)  alloc((size_t)NFLAT * 4);
  int*   counts = (int*)  alloc((size_t)NEXP * 4);
  int*   starts = (int*)  alloc((size_t)NEXP * 4);
  int*   rinfo  = (int*)  alloc((size_t)NFLAT * 4);
  int*   sortp  = (int*)  alloc((size_t)NFLAT * 4);
  unsigned short* a_buf = (unsigned short*)alloc((size_t)NFLAT * IDIM * 2);
  unsigned short* y_buf = (unsigned short*)alloc((size_t)NFLAT * HDIM * 2);
  (void)ws_size; (void)in_sizes; (void)n_in; (void)out_size;

  k_gating<<<T_TOK/16, 256, 0, stream>>>(hs, gw, hs_bf, tidx, tw);
  k_count_rank<<<NEXP, 64, 0, stream>>>(tidx, rankb, counts);
  k_build<<<1, 256, 0, stream>>>(tidx, rankb, counts, starts, rinfo, sortp);
  k_gemm1<<<dim3(12, NEXP), 256, 0, stream>>>(hs_bf, w13, counts, starts, rinfo, a_buf);
  k_gemm2<<<dim3(16, NEXP), 256, 0, stream>>>(a_buf, w2, counts, starts, y_buf);
  k_finalize<<<T_TOK, 256, 0, stream>>>(y_buf, sortp, tw, out);
}